// Round 13
// baseline (420.185 us; speedup 1.0000x reference)
//
#include <hip/hip_runtime.h>
#include <hip/hip_bf16.h>

// Problem constants
#define B_   8
#define NQ_  2048
#define NKV_ 2048
#define DQ_  512
#define DIN_ 512

using f32x4 = __attribute__((ext_vector_type(4))) float;
using f16   = _Float16;
using f16x4 = __attribute__((ext_vector_type(4))) _Float16;
using f16x8 = __attribute__((ext_vector_type(8))) _Float16;

__device__ __forceinline__ f32x4 mfma16f(f16x8 a, f16x8 b, f32x4 c) {
  return __builtin_amdgcn_mfma_f32_16x16x32_f16(a, b, c, 0, 0, 0);
}

// async global->LDS, 16B per lane. LDS dest is wave-uniform base (+lane*16 in HW).
__device__ __forceinline__ void gload_lds16(const void* g, void* l) {
  __builtin_amdgcn_global_load_lds(
      (const __attribute__((address_space(1))) void*)g,
      (__attribute__((address_space(3))) void*)l, 16, 0, 0);
}

// bijective XCD-aware remap (nwg % 8 == 0)
__device__ __forceinline__ int xcd_swz(int bid, int nwg) {
  const int c = nwg >> 3;
  return (bid & 7) * c + (bid >> 3);
}

// ---------------------------------------------------------------------------
// Fused projection GEMM (both projections in one launch, blockIdx.z selects):
//   z=0: qp = query @ W_proj^T + b_proj
//   z=1: km = x @ W_px^T + b_px + key ; AND (bx==0 blocks) emit xT tiles.
// ---------------------------------------------------------------------------
__global__ __launch_bounds__(256, 2)
void proj_gemm(const float* __restrict__ query, const float* __restrict__ W_proj,
               const float* __restrict__ b_proj, f16* __restrict__ qp,
               const float* __restrict__ x, const float* __restrict__ W_px,
               const float* __restrict__ b_px, const float* __restrict__ keyp,
               f16* __restrict__ km, f16* __restrict__ xTp)
{
  constexpr int PAD = 8;
  __shared__ f16 Ah[128][64 + PAD];
  __shared__ f16 Bh[128][64 + PAD];

  const bool second = (blockIdx.z == 1);
  const float* A    = second ? x    : query;
  const float* Bm   = second ? W_px : W_proj;
  const float* bias = second ? b_px : b_proj;
  f16*         C    = second ? km   : qp;

  const int tid  = threadIdx.x;
  const int lane = tid & 63;
  const int w    = tid >> 6;
  const int wr   = w >> 1;
  const int wc   = w & 1;
  const int brow = blockIdx.y * 128;
  const int bcol = blockIdx.x * 128;

  const float* Ag = A  + (size_t)brow * DQ_;
  const float* Bg = Bm + (size_t)bcol * DQ_;

  f32x4 acc[4][4] = {};

  const int sr = tid >> 4;
  const int sc = (tid & 15) * 4;

  float4 pa[8], pb[8];
#pragma unroll
  for (int p = 0; p < 8; ++p) {
    pa[p] = *(const float4*)(Ag + (size_t)(p * 16 + sr) * DQ_ + sc);
    pb[p] = *(const float4*)(Bg + (size_t)(p * 16 + sr) * DQ_ + sc);
  }

  const bool emitXT = second && (blockIdx.x == 0);

  for (int k0 = 0; k0 < DQ_; k0 += 64) {
    __syncthreads();
#pragma unroll
    for (int p = 0; p < 8; ++p) {
      const int r = p * 16 + sr;
      f16x4 ha, hb;
      ha[0] = (f16)pa[p].x; ha[1] = (f16)pa[p].y;
      ha[2] = (f16)pa[p].z; ha[3] = (f16)pa[p].w;
      hb[0] = (f16)pb[p].x; hb[1] = (f16)pb[p].y;
      hb[2] = (f16)pb[p].z; hb[3] = (f16)pb[p].w;
      *(f16x4*)&Ah[r][sc] = ha;
      *(f16x4*)&Bh[r][sc] = hb;
    }
    if (k0 + 64 < DQ_) {
#pragma unroll
      for (int p = 0; p < 8; ++p) {
        pa[p] = *(const float4*)(Ag + (size_t)(p * 16 + sr) * DQ_ + k0 + 64 + sc);
        pb[p] = *(const float4*)(Bg + (size_t)(p * 16 + sr) * DQ_ + k0 + 64 + sc);
      }
    }
    __syncthreads();
#pragma unroll
    for (int kk = 0; kk < 2; ++kk) {
      const int fr = lane & 15;
      const int fc = kk * 32 + (lane >> 4) * 8;
      f16x8 ah[4], bh[4];
#pragma unroll
      for (int m = 0; m < 4; ++m)
        ah[m] = *(const f16x8*)&Ah[wr * 64 + m * 16 + fr][fc];
#pragma unroll
      for (int n = 0; n < 4; ++n)
        bh[n] = *(const f16x8*)&Bh[wc * 64 + n * 16 + fr][fc];
#pragma unroll
      for (int m = 0; m < 4; ++m)
#pragma unroll
        for (int n = 0; n < 4; ++n)
          acc[m][n] = mfma16f(ah[m], bh[n], acc[m][n]);
    }

    if (emitXT) {
      const int dl = tid >> 2;
      const int j0 = (tid & 3) * 32;
      f16* dst = xTp + ((size_t)(brow >> 11) * DIN_ + k0 + dl) * NKV_
                     + (brow & (NKV_ - 1)) + j0;
#pragma unroll
      for (int v = 0; v < 4; ++v) {
        f16x8 tv;
#pragma unroll
        for (int e = 0; e < 8; ++e) tv[e] = Ah[j0 + v * 8 + e][dl];
        *(f16x8*)(dst + v * 8) = tv;
      }
    }
  }

#pragma unroll
  for (int m = 0; m < 4; ++m)
#pragma unroll
    for (int n = 0; n < 4; ++n)
#pragma unroll
      for (int r = 0; r < 4; ++r) {
        const int row_g = brow + wr * 64 + m * 16 + (lane >> 4) * 4 + r;
        const int col_g = bcol + wc * 64 + n * 16 + (lane & 15);
        float vv = acc[m][n][r] + bias[col_g];
        if (second) vv += keyp[(size_t)(row_g & (NKV_ - 1)) * DQ_ + col_g];
        C[(size_t)row_g * DQ_ + col_g] = (f16)vv;
      }
}

// ---------------------------------------------------------------------------
// Score GEMM: raw scores -> rawp; per-(row, 64-col-chunk) (max, sumexp)
// stats -> stats[R*32 + bx*4 + wcn]. Structure = proven R11 score.
// ---------------------------------------------------------------------------
__global__ __launch_bounds__(512, 4)
void score_gemm(const f16* __restrict__ qp, const f16* __restrict__ km,
                float* __restrict__ rawp, float2* __restrict__ stats)
{
  __shared__ f16 ABuf[2 * 8192];   // [parity][256 rows][32]
  __shared__ f16 BBuf[2 * 8192];

  const int swz  = xcd_swz(blockIdx.x, gridDim.x);   // 512 blocks
  const int bx   = swz & 7;           // NKV block (256)
  const int by   = (swz >> 3) & 7;    // NQ block (256)
  const int b    = swz >> 6;          // batch

  const int t    = threadIdx.x;       // 0..511
  const int lane = t & 63;
  const int w    = t >> 6;            // 0..7
  const int wr   = w >> 2;            // 0..1 (M: rows wr*128..+128)
  const int wcn  = w & 3;             // 0..3 (N: cols wcn*64..+64)
  const int brow = by * 256;
  const int bcol = bx * 256;
  const int fr   = lane & 15;
  const int q    = lane >> 4;
  const int slotE = ((q ^ (fr & 3)) * 8);

  const int srow = t >> 2;
  const int sig  = (t & 3) ^ (srow & 3);
  const f16* aG = qp + ((size_t)b * NQ_  + brow + srow) * DQ_ + sig * 8;
  const f16* bG = km + ((size_t)b * NKV_ + bcol + srow) * DQ_ + sig * 8;

#define STAGE_A(kc) do { \
    const f16* s_ = aG + (kc) * 32; \
    f16* d_ = ABuf + ((kc) & 1) * 8192 + w * 512; \
    gload_lds16(s_, d_); \
    gload_lds16(s_ + (size_t)128 * DQ_, d_ + 4096); } while (0)
#define STAGE_B(kc) do { \
    const f16* s_ = bG + (kc) * 32; \
    f16* d_ = BBuf + ((kc) & 1) * 8192 + w * 512; \
    gload_lds16(s_, d_); \
    gload_lds16(s_ + (size_t)128 * DQ_, d_ + 4096); } while (0)

  f32x4 acc[8][4] = {};

  STAGE_A(0); STAGE_B(0);
  asm volatile("s_waitcnt vmcnt(0)\n\ts_barrier" ::: "memory");

  for (int c = 0; c < 16; ++c) {
    if (c + 1 < 16) { STAGE_A(c + 1); STAGE_B(c + 1); }

    const f16* Ab = ABuf + (c & 1) * 8192;
    const f16* Bb = BBuf + (c & 1) * 8192;

    f16x8 bh[4];
#pragma unroll
    for (int ni = 0; ni < 4; ++ni)
      bh[ni] = *(const f16x8*)&Bb[(wcn * 64 + ni * 16 + fr) * 32 + slotE];

    __builtin_amdgcn_s_setprio(1);
#pragma unroll
    for (int mi = 0; mi < 8; ++mi) {
      const f16x8 ah = *(const f16x8*)&Ab[(wr * 128 + mi * 16 + fr) * 32 + slotE];
#pragma unroll
      for (int ni = 0; ni < 4; ++ni)
        acc[mi][ni] = mfma16f(ah, bh[ni], acc[mi][ni]);
    }
    __builtin_amdgcn_s_setprio(0);

    if (c + 1 < 16)
      asm volatile("s_waitcnt vmcnt(0)\n\ts_barrier" ::: "memory");
  }
#undef STAGE_A
#undef STAGE_B

  // ---- epilogue: per-row (max, sumexp) over this wave's 64 cols + raw write.
  // Row owned by the 16 lanes of a q-group (fr=0..15); shfl_xor 1/2/4/8 stays
  // within the group (q bits are lane bits 4-5).
  float* Cg = rawp + (size_t)b * NQ_ * NKV_;
#pragma unroll
  for (int mi = 0; mi < 8; ++mi)
#pragma unroll
    for (int r = 0; r < 4; ++r) {
      float m = fmaxf(fmaxf(acc[mi][0][r], acc[mi][1][r]),
                      fmaxf(acc[mi][2][r], acc[mi][3][r]));
#pragma unroll
      for (int off = 8; off; off >>= 1) m = fmaxf(m, __shfl_xor(m, off, 64));
      float s = __expf(acc[mi][0][r] - m) + __expf(acc[mi][1][r] - m)
              + __expf(acc[mi][2][r] - m) + __expf(acc[mi][3][r] - m);
#pragma unroll
      for (int off = 8; off; off >>= 1) s += __shfl_xor(s, off, 64);
      if (fr == 0) {
        const size_t R = (size_t)b * NQ_ + brow + wr * 128 + mi * 16 + q * 4 + r;
        stats[(R << 5) + bx * 4 + wcn] = make_float2(m, s);
      }
    }

#pragma unroll
  for (int mi = 0; mi < 8; ++mi)
#pragma unroll
    for (int ni = 0; ni < 4; ++ni)
#pragma unroll
      for (int r = 0; r < 4; ++r) {
        const int row_g = brow + wr * 128 + mi * 16 + q * 4 + r;
        const int col_g = bcol + wcn * 64 + ni * 16 + fr;
        Cg[(size_t)row_g * NKV_ + col_g] = acc[mi][ni][r];
      }
}

// ---------------------------------------------------------------------------
// Combine 32 per-chunk stats into per-row (m*, 1/s*). One thread per row.
// ---------------------------------------------------------------------------
__global__ void stats_reduce(const float2* __restrict__ stats,
                             float2* __restrict__ rowstats)
{
  const int R = blockIdx.x * 256 + threadIdx.x;   // 0..16383
  float2 v[32];
  float m = -1e30f;
#pragma unroll
  for (int i = 0; i < 32; ++i) {
    v[i] = stats[((size_t)R << 5) + i];
    m = fmaxf(m, v[i].x);
  }
  float s = 0.f;
#pragma unroll
  for (int i = 0; i < 32; ++i) s += v[i].y * __expf(v[i].x - m);
  rowstats[R] = make_float2(m, 1.0f / s);
}

// ---------------------------------------------------------------------------
// PV GEMM with on-the-fly softmax: A = exp(raw - m)*inv_s (fp32 raw + stats),
// reg-staged with exp under MFMA shadow, fp16 into swizzled LDS. B = xT via
// gload_lds (proven map). If attn_out != null, bx==0 blocks also write the
// normalized fp32 attn output.
// ---------------------------------------------------------------------------
__global__ __launch_bounds__(256, 2)
void pv_gemm(const float* __restrict__ raw, const float2* __restrict__ rowstats,
             const f16* __restrict__ xT, float* __restrict__ out,
             float* __restrict__ attn_out)
{
  __shared__ f16 At[2][128 * 64];
  __shared__ f16 Bt[2][128 * 64];

  const int swz  = xcd_swz(blockIdx.x, gridDim.x);
  const int bx   = swz & 3;           // DIN block
  const int by   = (swz >> 2) & 15;   // NQ block
  const int b    = swz >> 6;          // batch

  const int t    = threadIdx.x;
  const int lane = t & 63;
  const int w    = t >> 6;
  const int wr   = w >> 1;
  const int wc   = w & 1;
  const int brow = by * 128;   // q rows
  const int bcol = bx * 128;   // din cols
  const int fr   = lane & 15;
  const int q    = lane >> 4;

  // B staging map (proven)
  const int srow = t >> 3;
  const int sigB = (t & 7) ^ (srow & 7);
  const f16* bG = xT + (size_t)b * DIN_ * NKV_ + (size_t)(bcol + srow) * NKV_ + sigB * 8;

  // A: raw fp32, thread t covers rows r0+j*16 (j=0..7), cols c4*4..+3
  const int c4 = t & 15;
  const int r0 = t >> 4;              // 0..15
  const size_t Rbase = (size_t)b * NQ_ + brow;
  const float* aB = raw + (Rbase + r0) * NKV_ + c4 * 4;
  float*       nB = attn_out + (Rbase + r0) * NKV_ + c4 * 4;  // unused if null
  float2 rs[8];
#pragma unroll
  for (int j = 0; j < 8; ++j) rs[j] = rowstats[Rbase + r0 + j * 16];

  const bool wrN = (attn_out != nullptr) && (bx == 0);

  float4 av[8];
#define PV_LOADA(kc) do { \
    _Pragma("unroll") for (int j = 0; j < 8; ++j) \
      av[j] = *(const float4*)(aB + (size_t)j * 16 * NKV_ + (kc) * 64); } while (0)
#define PV_STAGEB(kc, buf) do { \
    const f16* b_ = bG + (size_t)(kc) * 64; \
    f16* bl_ = Bt[buf] + w * 512; \
    _Pragma("unroll") for (int i = 0; i < 4; ++i) \
      gload_lds16(b_ + (size_t)i * 32 * NKV_, bl_ + i * 2048); } while (0)
#define PV_PROCA(kc, buf) do { \
    _Pragma("unroll") for (int j = 0; j < 8; ++j) { \
      const int rj = r0 + j * 16; \
      float4 n_; \
      n_.x = __expf(av[j].x - rs[j].x) * rs[j].y; \
      n_.y = __expf(av[j].y - rs[j].x) * rs[j].y; \
      n_.z = __expf(av[j].z - rs[j].x) * rs[j].y; \
      n_.w = __expf(av[j].w - rs[j].x) * rs[j].y; \
      if (wrN) *(float4*)(nB + (size_t)j * 16 * NKV_ + (kc) * 64) = n_; \
      f16x4 hv; hv[0] = (f16)n_.x; hv[1] = (f16)n_.y; \
      hv[2] = (f16)n_.z; hv[3] = (f16)n_.w; \
      *(f16x4*)&At[buf][rj * 64 + (((c4 >> 1) ^ (rj & 7)) * 8) + (c4 & 1) * 4] = hv; \
    } } while (0)

  f32x4 acc[4][4] = {};

  // prologue: chunk 0
  PV_LOADA(0); PV_STAGEB(0, 0); PV_PROCA(0, 0);
  __syncthreads();

  for (int ks = 0; ks < NKV_ / 64; ++ks) {
    const int cur = ks & 1;
    if (ks + 1 < NKV_ / 64) { PV_LOADA(ks + 1); PV_STAGEB(ks + 1, cur ^ 1); }

    const f16* Ac = At[cur];
    const f16* Bc = Bt[cur];
#pragma unroll
    for (int kk = 0; kk < 2; ++kk) {
      f16x8 ah[4], bh[4];
#pragma unroll
      for (int m = 0; m < 4; ++m) {
        const int rt = wr * 64 + m * 16 + fr;
        ah[m] = *(const f16x8*)&Ac[rt * 64 + (((kk * 4 + q) ^ (rt & 7)) * 8)];
      }
#pragma unroll
      for (int n = 0; n < 4; ++n) {
        const int rt = wc * 64 + n * 16 + fr;
        bh[n] = *(const f16x8*)&Bc[rt * 64 + (((kk * 4 + q) ^ (rt & 7)) * 8)];
      }
      __builtin_amdgcn_s_setprio(1);
#pragma unroll
      for (int m = 0; m < 4; ++m)
#pragma unroll
        for (int n = 0; n < 4; ++n)
          acc[m][n] = mfma16f(ah[m], bh[n], acc[m][n]);
      __builtin_amdgcn_s_setprio(0);
    }
    if (ks + 1 < NKV_ / 64) PV_PROCA(ks + 1, cur ^ 1);
    __syncthreads();
  }
#undef PV_LOADA
#undef PV_STAGEB
#undef PV_PROCA

  float* Cg = out + (size_t)b * NQ_ * DIN_;
#pragma unroll
  for (int m = 0; m < 4; ++m)
#pragma unroll
    for (int n = 0; n < 4; ++n)
#pragma unroll
      for (int r = 0; r < 4; ++r) {
        const int row_g = brow + wr * 64 + m * 16 + q * 4 + r;
        const int col_g = bcol + wc * 64 + n * 16 + fr;
        Cg[(size_t)row_g * DIN_ + col_g] = acc[m][n][r];
      }
}

// ---------------------------------------------------------------------------
// Fallback (small ws): normalize raw scores in place in the attn region.
// ---------------------------------------------------------------------------
__global__ void normalize_attn(float* __restrict__ attn,
                               const float2* __restrict__ rowstats)
{
  const size_t i4 = (size_t)blockIdx.x * 256 + threadIdx.x;
  const int R = (int)(i4 >> 9);                 // 512 float4 per row
  const float2 rs = rowstats[R];
  float4 v = ((const float4*)attn)[i4];
  v.x = __expf(v.x - rs.x) * rs.y;
  v.y = __expf(v.y - rs.x) * rs.y;
  v.z = __expf(v.z - rs.x) * rs.y;
  v.w = __expf(v.w - rs.x) * rs.y;
  ((float4*)attn)[i4] = v;
}

// ---------------------------------------------------------------------------
extern "C" void kernel_launch(void* const* d_in, const int* in_sizes, int n_in,
                              void* d_out, int out_size, void* d_ws, size_t ws_size,
                              hipStream_t stream)
{
  (void)in_sizes; (void)n_in; (void)out_size;
  const float* query  = (const float*)d_in[0];  // [8, 2048, 512]
  const float* key    = (const float*)d_in[1];  // [2048, 512]
  const float* x      = (const float*)d_in[2];  // [8, 2048, 512]
  const float* W_proj = (const float*)d_in[3];  // [512, 512]
  const float* b_proj = (const float*)d_in[4];  // [512]
  const float* W_px   = (const float*)d_in[5];  // [512, 512]
  const float* b_px   = (const float*)d_in[6];  // [512]

  float* out  = (float*)d_out;                          // [8, 2048, 512]
  float* attn = out + (size_t)B_ * NQ_ * DIN_;          // [8, 2048, 2048]

  const size_t PQE  = (size_t)B_ * NQ_ * DQ_;           // 8.39M elements
  const size_t ROWS = (size_t)B_ * NQ_;                 // 16384

  // ws layout: xT | qp | km | stats | rowstats | [raw if it fits]
  f16*    xT       = (f16*)d_ws;                 // PQE f16
  f16*    qp       = xT + PQE;                   // PQE f16
  f16*    km       = qp + PQE;                   // PQE f16
  float2* stats    = (float2*)(km + PQE);        // ROWS*32
  float2* rowstats = stats + ROWS * 32;          // ROWS
  float*  rawws    = (float*)(rowstats + ROWS);  // ROWS*NKV fp32 (optional)

  const size_t need = (size_t)((char*)(rawws + ROWS * NKV_) - (char*)d_ws);
  const bool big = (ws_size >= need);

  float* rawp     = big ? rawws : attn;   // where raw scores live
  float* attn_out = big ? attn  : nullptr; // pv writes normalized attn iff big

  // fused projections (z=0: qp; z=1: km + xT emission)
  proj_gemm<<<dim3(DQ_ / 128, (B_ * NQ_) / 128, 2), 256, 0, stream>>>(
      query, W_proj, b_proj, qp, x, W_px, b_px, key, km, xT);

  // raw scores + per-chunk stats
  score_gemm<<<(NKV_ / 256) * (NQ_ / 256) * B_, 512, 0, stream>>>(
      qp, km, rawp, stats);

  // per-row (m*, 1/s*)
  stats_reduce<<<(int)(ROWS / 256), 256, 0, stream>>>(stats, rowstats);

  // PV with on-the-fly normalization (+ attn write in big path)
  pv_gemm<<<(DIN_ / 128) * (NQ_ / 128) * B_, 256, 0, stream>>>(
      rawp, rowstats, xT, out, attn_out);

  // small-ws fallback: normalize raw scores in place in d_out
  if (!big)
    normalize_attn<<<(int)(ROWS * NKV_ / 4 / 256), 256, 0, stream>>>(
        attn, rowstats);
}

// Round 14
// 257.645 us; speedup vs baseline: 1.6309x; 1.6309x over previous
//
#include <hip/hip_runtime.h>
#include <hip/hip_bf16.h>

// Problem constants
#define B_   8
#define NQ_  2048
#define NKV_ 2048
#define DQ_  512
#define DIN_ 512

using f32x4 = __attribute__((ext_vector_type(4))) float;
using f16   = _Float16;
using f16x4 = __attribute__((ext_vector_type(4))) _Float16;
using f16x8 = __attribute__((ext_vector_type(8))) _Float16;

__device__ __forceinline__ f32x4 mfma16f(f16x8 a, f16x8 b, f32x4 c) {
  return __builtin_amdgcn_mfma_f32_16x16x32_f16(a, b, c, 0, 0, 0);
}

// async global->LDS, 16B per lane. LDS dest is wave-uniform base (+lane*16 in HW).
__device__ __forceinline__ void gload_lds16(const void* g, void* l) {
  __builtin_amdgcn_global_load_lds(
      (const __attribute__((address_space(1))) void*)g,
      (__attribute__((address_space(3))) void*)l, 16, 0, 0);
}

// bijective XCD-aware remap (nwg % 8 == 0)
__device__ __forceinline__ int xcd_swz(int bid, int nwg) {
  const int c = nwg >> 3;
  return (bid & 7) * c + (bid >> 3);
}

// ---------------------------------------------------------------------------
// Fused projection GEMM (both projections in one launch, blockIdx.z selects):
//   z=0: qp = query @ W_proj^T + b_proj
//   z=1: km = x @ W_px^T + b_px + key ; AND (bx==0 blocks) emit xT tiles.
// ---------------------------------------------------------------------------
__global__ __launch_bounds__(256, 2)
void proj_gemm(const float* __restrict__ query, const float* __restrict__ W_proj,
               const float* __restrict__ b_proj, f16* __restrict__ qp,
               const float* __restrict__ x, const float* __restrict__ W_px,
               const float* __restrict__ b_px, const float* __restrict__ keyp,
               f16* __restrict__ km, f16* __restrict__ xTp)
{
  constexpr int PAD = 8;
  __shared__ f16 Ah[128][64 + PAD];
  __shared__ f16 Bh[128][64 + PAD];

  const bool second = (blockIdx.z == 1);
  const float* A    = second ? x    : query;
  const float* Bm   = second ? W_px : W_proj;
  const float* bias = second ? b_px : b_proj;
  f16*         C    = second ? km   : qp;

  const int tid  = threadIdx.x;
  const int lane = tid & 63;
  const int w    = tid >> 6;
  const int wr   = w >> 1;
  const int wc   = w & 1;
  const int brow = blockIdx.y * 128;
  const int bcol = blockIdx.x * 128;

  const float* Ag = A  + (size_t)brow * DQ_;
  const float* Bg = Bm + (size_t)bcol * DQ_;

  f32x4 acc[4][4] = {};

  const int sr = tid >> 4;
  const int sc = (tid & 15) * 4;

  float4 pa[8], pb[8];
#pragma unroll
  for (int p = 0; p < 8; ++p) {
    pa[p] = *(const float4*)(Ag + (size_t)(p * 16 + sr) * DQ_ + sc);
    pb[p] = *(const float4*)(Bg + (size_t)(p * 16 + sr) * DQ_ + sc);
  }

  const bool emitXT = second && (blockIdx.x == 0);

  for (int k0 = 0; k0 < DQ_; k0 += 64) {
    __syncthreads();
#pragma unroll
    for (int p = 0; p < 8; ++p) {
      const int r = p * 16 + sr;
      f16x4 ha, hb;
      ha[0] = (f16)pa[p].x; ha[1] = (f16)pa[p].y;
      ha[2] = (f16)pa[p].z; ha[3] = (f16)pa[p].w;
      hb[0] = (f16)pb[p].x; hb[1] = (f16)pb[p].y;
      hb[2] = (f16)pb[p].z; hb[3] = (f16)pb[p].w;
      *(f16x4*)&Ah[r][sc] = ha;
      *(f16x4*)&Bh[r][sc] = hb;
    }
    if (k0 + 64 < DQ_) {
#pragma unroll
      for (int p = 0; p < 8; ++p) {
        pa[p] = *(const float4*)(Ag + (size_t)(p * 16 + sr) * DQ_ + k0 + 64 + sc);
        pb[p] = *(const float4*)(Bg + (size_t)(p * 16 + sr) * DQ_ + k0 + 64 + sc);
      }
    }
    __syncthreads();
#pragma unroll
    for (int kk = 0; kk < 2; ++kk) {
      const int fr = lane & 15;
      const int fc = kk * 32 + (lane >> 4) * 8;
      f16x8 ah[4], bh[4];
#pragma unroll
      for (int m = 0; m < 4; ++m)
        ah[m] = *(const f16x8*)&Ah[wr * 64 + m * 16 + fr][fc];
#pragma unroll
      for (int n = 0; n < 4; ++n)
        bh[n] = *(const f16x8*)&Bh[wc * 64 + n * 16 + fr][fc];
#pragma unroll
      for (int m = 0; m < 4; ++m)
#pragma unroll
        for (int n = 0; n < 4; ++n)
          acc[m][n] = mfma16f(ah[m], bh[n], acc[m][n]);
    }

    if (emitXT) {
      const int dl = tid >> 2;
      const int j0 = (tid & 3) * 32;
      f16* dst = xTp + ((size_t)(brow >> 11) * DIN_ + k0 + dl) * NKV_
                     + (brow & (NKV_ - 1)) + j0;
#pragma unroll
      for (int v = 0; v < 4; ++v) {
        f16x8 tv;
#pragma unroll
        for (int e = 0; e < 8; ++e) tv[e] = Ah[j0 + v * 8 + e][dl];
        *(f16x8*)(dst + v * 8) = tv;
      }
    }
  }

#pragma unroll
  for (int m = 0; m < 4; ++m)
#pragma unroll
    for (int n = 0; n < 4; ++n)
#pragma unroll
      for (int r = 0; r < 4; ++r) {
        const int row_g = brow + wr * 64 + m * 16 + (lane >> 4) * 4 + r;
        const int col_g = bcol + wc * 64 + n * 16 + (lane & 15);
        float vv = acc[m][n][r] + bias[col_g];
        if (second) vv += keyp[(size_t)(row_g & (NKV_ - 1)) * DQ_ + col_g];
        C[(size_t)row_g * DQ_ + col_g] = (f16)vv;
      }
}

// ---------------------------------------------------------------------------
// Score GEMM: raw scores -> rawp; per-(row, 64-col-chunk) (max, sumexp)
// stats -> stats[R*32 + bx*4 + wcn]. Structure = proven R11 score.
// launch_bounds (512,2): R13's (512,4) capped VGPR at 64 -> acc spill (752MB
// scratch writes, MfmaUtil 0.3%). Needs ~140 VGPR.
// ---------------------------------------------------------------------------
__global__ __launch_bounds__(512, 2)
void score_gemm(const f16* __restrict__ qp, const f16* __restrict__ km,
                float* __restrict__ rawp, float2* __restrict__ stats)
{
  __shared__ f16 ABuf[2 * 8192];   // [parity][256 rows][32]
  __shared__ f16 BBuf[2 * 8192];

  const int swz  = xcd_swz(blockIdx.x, gridDim.x);   // 512 blocks
  const int bx   = swz & 7;           // NKV block (256)
  const int by   = (swz >> 3) & 7;    // NQ block (256)
  const int b    = swz >> 6;          // batch

  const int t    = threadIdx.x;       // 0..511
  const int lane = t & 63;
  const int w    = t >> 6;            // 0..7
  const int wr   = w >> 2;            // 0..1 (M: rows wr*128..+128)
  const int wcn  = w & 3;             // 0..3 (N: cols wcn*64..+64)
  const int brow = by * 256;
  const int bcol = bx * 256;
  const int fr   = lane & 15;
  const int q    = lane >> 4;
  const int slotE = ((q ^ (fr & 3)) * 8);

  const int srow = t >> 2;
  const int sig  = (t & 3) ^ (srow & 3);
  const f16* aG = qp + ((size_t)b * NQ_  + brow + srow) * DQ_ + sig * 8;
  const f16* bG = km + ((size_t)b * NKV_ + bcol + srow) * DQ_ + sig * 8;

#define STAGE_A(kc) do { \
    const f16* s_ = aG + (kc) * 32; \
    f16* d_ = ABuf + ((kc) & 1) * 8192 + w * 512; \
    gload_lds16(s_, d_); \
    gload_lds16(s_ + (size_t)128 * DQ_, d_ + 4096); } while (0)
#define STAGE_B(kc) do { \
    const f16* s_ = bG + (kc) * 32; \
    f16* d_ = BBuf + ((kc) & 1) * 8192 + w * 512; \
    gload_lds16(s_, d_); \
    gload_lds16(s_ + (size_t)128 * DQ_, d_ + 4096); } while (0)

  f32x4 acc[8][4] = {};

  STAGE_A(0); STAGE_B(0);
  asm volatile("s_waitcnt vmcnt(0)\n\ts_barrier" ::: "memory");

  for (int c = 0; c < 16; ++c) {
    if (c + 1 < 16) { STAGE_A(c + 1); STAGE_B(c + 1); }

    const f16* Ab = ABuf + (c & 1) * 8192;
    const f16* Bb = BBuf + (c & 1) * 8192;

    f16x8 bh[4];
#pragma unroll
    for (int ni = 0; ni < 4; ++ni)
      bh[ni] = *(const f16x8*)&Bb[(wcn * 64 + ni * 16 + fr) * 32 + slotE];

    __builtin_amdgcn_s_setprio(1);
#pragma unroll
    for (int mi = 0; mi < 8; ++mi) {
      const f16x8 ah = *(const f16x8*)&Ab[(wr * 128 + mi * 16 + fr) * 32 + slotE];
#pragma unroll
      for (int ni = 0; ni < 4; ++ni)
        acc[mi][ni] = mfma16f(ah, bh[ni], acc[mi][ni]);
    }
    __builtin_amdgcn_s_setprio(0);

    if (c + 1 < 16)
      asm volatile("s_waitcnt vmcnt(0)\n\ts_barrier" ::: "memory");
  }
#undef STAGE_A
#undef STAGE_B

  // ---- epilogue: per-row (max, sumexp) over this wave's 64 cols + raw write.
  float* Cg = rawp + (size_t)b * NQ_ * NKV_;
#pragma unroll
  for (int mi = 0; mi < 8; ++mi)
#pragma unroll
    for (int r = 0; r < 4; ++r) {
      float m = fmaxf(fmaxf(acc[mi][0][r], acc[mi][1][r]),
                      fmaxf(acc[mi][2][r], acc[mi][3][r]));
#pragma unroll
      for (int off = 8; off; off >>= 1) m = fmaxf(m, __shfl_xor(m, off, 64));
      float s = __expf(acc[mi][0][r] - m) + __expf(acc[mi][1][r] - m)
              + __expf(acc[mi][2][r] - m) + __expf(acc[mi][3][r] - m);
#pragma unroll
      for (int off = 8; off; off >>= 1) s += __shfl_xor(s, off, 64);
      if (fr == 0) {
        const size_t R = (size_t)b * NQ_ + brow + wr * 128 + mi * 16 + q * 4 + r;
        stats[(R << 5) + bx * 4 + wcn] = make_float2(m, s);
      }
    }

#pragma unroll
  for (int mi = 0; mi < 8; ++mi)
#pragma unroll
    for (int ni = 0; ni < 4; ++ni)
#pragma unroll
      for (int r = 0; r < 4; ++r) {
        const int row_g = brow + wr * 128 + mi * 16 + q * 4 + r;
        const int col_g = bcol + wcn * 64 + ni * 16 + fr;
        Cg[(size_t)row_g * NKV_ + col_g] = acc[mi][ni][r];
      }
}

// ---------------------------------------------------------------------------
// Combine 32 per-chunk stats into per-row (m*, 1/s*). One thread per row.
// ---------------------------------------------------------------------------
__global__ void stats_reduce(const float2* __restrict__ stats,
                             float2* __restrict__ rowstats)
{
  const int R = blockIdx.x * 256 + threadIdx.x;   // 0..16383
  float2 v[32];
  float m = -1e30f;
#pragma unroll
  for (int i = 0; i < 32; ++i) {
    v[i] = stats[((size_t)R << 5) + i];
    m = fmaxf(m, v[i].x);
  }
  float s = 0.f;
#pragma unroll
  for (int i = 0; i < 32; ++i) s += v[i].y * __expf(v[i].x - m);
  rowstats[R] = make_float2(m, 1.0f / s);
}

// ---------------------------------------------------------------------------
// PV GEMM with on-the-fly softmax: A = exp(raw - m)*inv_s (fp32 raw + stats),
// reg-staged with exp under MFMA shadow, fp16 into swizzled LDS. B = xT via
// gload_lds (proven map). If attn_out != null, bx==0 blocks also write the
// normalized fp32 attn output.
// ---------------------------------------------------------------------------
__global__ __launch_bounds__(256, 2)
void pv_gemm(const float* __restrict__ raw, const float2* __restrict__ rowstats,
             const f16* __restrict__ xT, float* __restrict__ out,
             float* __restrict__ attn_out)
{
  __shared__ f16 At[2][128 * 64];
  __shared__ f16 Bt[2][128 * 64];

  const int swz  = xcd_swz(blockIdx.x, gridDim.x);
  const int bx   = swz & 3;           // DIN block
  const int by   = (swz >> 2) & 15;   // NQ block
  const int b    = swz >> 6;          // batch

  const int t    = threadIdx.x;
  const int lane = t & 63;
  const int w    = t >> 6;
  const int wr   = w >> 1;
  const int wc   = w & 1;
  const int brow = by * 128;   // q rows
  const int bcol = bx * 128;   // din cols
  const int fr   = lane & 15;
  const int q    = lane >> 4;

  // B staging map (proven)
  const int srow = t >> 3;
  const int sigB = (t & 7) ^ (srow & 7);
  const f16* bG = xT + (size_t)b * DIN_ * NKV_ + (size_t)(bcol + srow) * NKV_ + sigB * 8;

  // A: raw fp32, thread t covers rows r0+j*16 (j=0..7), cols c4*4..+3
  const int c4 = t & 15;
  const int r0 = t >> 4;              // 0..15
  const size_t Rbase = (size_t)b * NQ_ + brow;
  const float* aB = raw + (Rbase + r0) * NKV_ + c4 * 4;
  float*       nB = attn_out + (Rbase + r0) * NKV_ + c4 * 4;  // unused if null
  float2 rs[8];
#pragma unroll
  for (int j = 0; j < 8; ++j) rs[j] = rowstats[Rbase + r0 + j * 16];

  const bool wrN = (attn_out != nullptr) && (bx == 0);

  float4 av[8];
#define PV_LOADA(kc) do { \
    _Pragma("unroll") for (int j = 0; j < 8; ++j) \
      av[j] = *(const float4*)(aB + (size_t)j * 16 * NKV_ + (kc) * 64); } while (0)
#define PV_STAGEB(kc, buf) do { \
    const f16* b_ = bG + (size_t)(kc) * 64; \
    f16* bl_ = Bt[buf] + w * 512; \
    _Pragma("unroll") for (int i = 0; i < 4; ++i) \
      gload_lds16(b_ + (size_t)i * 32 * NKV_, bl_ + i * 2048); } while (0)
#define PV_PROCA(kc, buf) do { \
    _Pragma("unroll") for (int j = 0; j < 8; ++j) { \
      const int rj = r0 + j * 16; \
      float4 n_; \
      n_.x = __expf(av[j].x - rs[j].x) * rs[j].y; \
      n_.y = __expf(av[j].y - rs[j].x) * rs[j].y; \
      n_.z = __expf(av[j].z - rs[j].x) * rs[j].y; \
      n_.w = __expf(av[j].w - rs[j].x) * rs[j].y; \
      if (wrN) *(float4*)(nB + (size_t)j * 16 * NKV_ + (kc) * 64) = n_; \
      f16x4 hv; hv[0] = (f16)n_.x; hv[1] = (f16)n_.y; \
      hv[2] = (f16)n_.z; hv[3] = (f16)n_.w; \
      *(f16x4*)&At[buf][rj * 64 + (((c4 >> 1) ^ (rj & 7)) * 8) + (c4 & 1) * 4] = hv; \
    } } while (0)

  f32x4 acc[4][4] = {};

  // prologue: chunk 0
  PV_LOADA(0); PV_STAGEB(0, 0); PV_PROCA(0, 0);
  __syncthreads();

  for (int ks = 0; ks < NKV_ / 64; ++ks) {
    const int cur = ks & 1;
    if (ks + 1 < NKV_ / 64) { PV_LOADA(ks + 1); PV_STAGEB(ks + 1, cur ^ 1); }

    const f16* Ac = At[cur];
    const f16* Bc = Bt[cur];
#pragma unroll
    for (int kk = 0; kk < 2; ++kk) {
      f16x8 ah[4], bh[4];
#pragma unroll
      for (int m = 0; m < 4; ++m) {
        const int rt = wr * 64 + m * 16 + fr;
        ah[m] = *(const f16x8*)&Ac[rt * 64 + (((kk * 4 + q) ^ (rt & 7)) * 8)];
      }
#pragma unroll
      for (int n = 0; n < 4; ++n) {
        const int rt = wc * 64 + n * 16 + fr;
        bh[n] = *(const f16x8*)&Bc[rt * 64 + (((kk * 4 + q) ^ (rt & 7)) * 8)];
      }
      __builtin_amdgcn_s_setprio(1);
#pragma unroll
      for (int m = 0; m < 4; ++m)
#pragma unroll
        for (int n = 0; n < 4; ++n)
          acc[m][n] = mfma16f(ah[m], bh[n], acc[m][n]);
      __builtin_amdgcn_s_setprio(0);
    }
    if (ks + 1 < NKV_ / 64) PV_PROCA(ks + 1, cur ^ 1);
    __syncthreads();
  }
#undef PV_LOADA
#undef PV_STAGEB
#undef PV_PROCA

  float* Cg = out + (size_t)b * NQ_ * DIN_;
#pragma unroll
  for (int m = 0; m < 4; ++m)
#pragma unroll
    for (int n = 0; n < 4; ++n)
#pragma unroll
      for (int r = 0; r < 4; ++r) {
        const int row_g = brow + wr * 64 + m * 16 + q * 4 + r;
        const int col_g = bcol + wc * 64 + n * 16 + fr;
        Cg[(size_t)row_g * DIN_ + col_g] = acc[m][n][r];
      }
}

// ---------------------------------------------------------------------------
// Fallback (small ws): normalize raw scores in place in the attn region.
// ---------------------------------------------------------------------------
__global__ void normalize_attn(float* __restrict__ attn,
                               const float2* __restrict__ rowstats)
{
  const size_t i4 = (size_t)blockIdx.x * 256 + threadIdx.x;
  const int R = (int)(i4 >> 9);                 // 512 float4 per row
  const float2 rs = rowstats[R];
  float4 v = ((const float4*)attn)[i4];
  v.x = __expf(v.x - rs.x) * rs.y;
  v.y = __expf(v.y - rs.x) * rs.y;
  v.z = __expf(v.z - rs.x) * rs.y;
  v.w = __expf(v.w - rs.x) * rs.y;
  ((float4*)attn)[i4] = v;
}

// ---------------------------------------------------------------------------
extern "C" void kernel_launch(void* const* d_in, const int* in_sizes, int n_in,
                              void* d_out, int out_size, void* d_ws, size_t ws_size,
                              hipStream_t stream)
{
  (void)in_sizes; (void)n_in; (void)out_size;
  const float* query  = (const float*)d_in[0];  // [8, 2048, 512]
  const float* key    = (const float*)d_in[1];  // [2048, 512]
  const float* x      = (const float*)d_in[2];  // [8, 2048, 512]
  const float* W_proj = (const float*)d_in[3];  // [512, 512]
  const float* b_proj = (const float*)d_in[4];  // [512]
  const float* W_px   = (const float*)d_in[5];  // [512, 512]
  const float* b_px   = (const float*)d_in[6];  // [512]

  float* out  = (float*)d_out;                          // [8, 2048, 512]
  float* attn = out + (size_t)B_ * NQ_ * DIN_;          // [8, 2048, 2048]

  const size_t PQE  = (size_t)B_ * NQ_ * DQ_;           // 8.39M elements
  const size_t ROWS = (size_t)B_ * NQ_;                 // 16384

  // ws layout: xT | qp | km | stats | rowstats | [raw if it fits]
  f16*    xT       = (f16*)d_ws;                 // PQE f16
  f16*    qp       = xT + PQE;                   // PQE f16
  f16*    km       = qp + PQE;                   // PQE f16
  float2* stats    = (float2*)(km + PQE);        // ROWS*32
  float2* rowstats = stats + ROWS * 32;          // ROWS
  float*  rawws    = (float*)(rowstats + ROWS);  // ROWS*NKV fp32 (optional)

  const size_t need = (size_t)((char*)(rawws + ROWS * NKV_) - (char*)d_ws);
  const bool big = (ws_size >= need);

  float* rawp     = big ? rawws : attn;    // where raw scores live
  float* attn_out = big ? attn  : nullptr; // pv writes normalized attn iff big

  // fused projections (z=0: qp; z=1: km + xT emission)
  proj_gemm<<<dim3(DQ_ / 128, (B_ * NQ_) / 128, 2), 256, 0, stream>>>(
      query, W_proj, b_proj, qp, x, W_px, b_px, key, km, xT);

  // raw scores + per-chunk stats
  score_gemm<<<(NKV_ / 256) * (NQ_ / 256) * B_, 512, 0, stream>>>(
      qp, km, rawp, stats);

  // per-row (m*, 1/s*)
  stats_reduce<<<(int)(ROWS / 256), 256, 0, stream>>>(stats, rowstats);

  // PV with on-the-fly normalization (+ attn write in big path)
  pv_gemm<<<(DIN_ / 128) * (NQ_ / 128) * B_, 256, 0, stream>>>(
      rawp, rowstats, xT, out, attn_out);

  // small-ws fallback: normalize raw scores in place in d_out
  if (!big)
    normalize_attn<<<(int)(ROWS * NKV_ / 4 / 256), 256, 0, stream>>>(
        attn, rowstats);
}

// Round 15
// 226.501 us; speedup vs baseline: 1.8551x; 1.1375x over previous
//
#include <hip/hip_runtime.h>
#include <hip/hip_bf16.h>

// Problem constants
#define B_   8
#define NQ_  2048
#define NKV_ 2048
#define DQ_  512
#define DIN_ 512

using f32x4 = __attribute__((ext_vector_type(4))) float;
using f16   = _Float16;
using f16x4 = __attribute__((ext_vector_type(4))) _Float16;
using f16x8 = __attribute__((ext_vector_type(8))) _Float16;

__device__ __forceinline__ f32x4 mfma16f(f16x8 a, f16x8 b, f32x4 c) {
  return __builtin_amdgcn_mfma_f32_16x16x32_f16(a, b, c, 0, 0, 0);
}

// async global->LDS, 16B per lane. LDS dest is wave-uniform base (+lane*16 in HW).
__device__ __forceinline__ void gload_lds16(const void* g, void* l) {
  __builtin_amdgcn_global_load_lds(
      (const __attribute__((address_space(1))) void*)g,
      (__attribute__((address_space(3))) void*)l, 16, 0, 0);
}

// bijective XCD-aware remap (nwg % 8 == 0)
__device__ __forceinline__ int xcd_swz(int bid, int nwg) {
  const int c = nwg >> 3;
  return (bid & 7) * c + (bid >> 3);
}

// ---------------------------------------------------------------------------
// Projection GEMM: C[m,n] = sum_k A[m,k]*B[n,k] + bias[n] (+ key), fp32 in,
// fp16 out, SINGLE fp16 product. T14 issue-early reg preload of next K-tile.
// EPI: 1 +bias[n]; 2 +bias[n] + key[(m&2047)*512+n]
// ---------------------------------------------------------------------------
template<int EPI>
__global__ __launch_bounds__(256, 2)
void proj_gemm(const float* __restrict__ A, const float* __restrict__ Bm,
               f16* __restrict__ C,
               const float* __restrict__ bias, const float* __restrict__ keyp)
{
  constexpr int PAD = 8;
  __shared__ f16 Ah[128][64 + PAD];
  __shared__ f16 Bh[128][64 + PAD];

  const int tid  = threadIdx.x;
  const int lane = tid & 63;
  const int w    = tid >> 6;
  const int wr   = w >> 1;
  const int wc   = w & 1;
  const int brow = blockIdx.y * 128;
  const int bcol = blockIdx.x * 128;

  const float* Ag = A  + (size_t)brow * DQ_;
  const float* Bg = Bm + (size_t)bcol * DQ_;

  f32x4 acc[4][4] = {};

  const int sr = tid >> 4;
  const int sc = (tid & 15) * 4;

  float4 pa[8], pb[8];
#pragma unroll
  for (int p = 0; p < 8; ++p) {
    pa[p] = *(const float4*)(Ag + (size_t)(p * 16 + sr) * DQ_ + sc);
    pb[p] = *(const float4*)(Bg + (size_t)(p * 16 + sr) * DQ_ + sc);
  }

  for (int k0 = 0; k0 < DQ_; k0 += 64) {
    __syncthreads();
#pragma unroll
    for (int p = 0; p < 8; ++p) {
      const int r = p * 16 + sr;
      f16x4 ha, hb;
      ha[0] = (f16)pa[p].x; ha[1] = (f16)pa[p].y;
      ha[2] = (f16)pa[p].z; ha[3] = (f16)pa[p].w;
      hb[0] = (f16)pb[p].x; hb[1] = (f16)pb[p].y;
      hb[2] = (f16)pb[p].z; hb[3] = (f16)pb[p].w;
      *(f16x4*)&Ah[r][sc] = ha;
      *(f16x4*)&Bh[r][sc] = hb;
    }
    if (k0 + 64 < DQ_) {
#pragma unroll
      for (int p = 0; p < 8; ++p) {
        pa[p] = *(const float4*)(Ag + (size_t)(p * 16 + sr) * DQ_ + k0 + 64 + sc);
        pb[p] = *(const float4*)(Bg + (size_t)(p * 16 + sr) * DQ_ + k0 + 64 + sc);
      }
    }
    __syncthreads();
#pragma unroll
    for (int kk = 0; kk < 2; ++kk) {
      const int fr = lane & 15;
      const int fc = kk * 32 + (lane >> 4) * 8;
      f16x8 ah[4], bh[4];
#pragma unroll
      for (int m = 0; m < 4; ++m)
        ah[m] = *(const f16x8*)&Ah[wr * 64 + m * 16 + fr][fc];
#pragma unroll
      for (int n = 0; n < 4; ++n)
        bh[n] = *(const f16x8*)&Bh[wc * 64 + n * 16 + fr][fc];
#pragma unroll
      for (int m = 0; m < 4; ++m)
#pragma unroll
        for (int n = 0; n < 4; ++n)
          acc[m][n] = mfma16f(ah[m], bh[n], acc[m][n]);
    }
  }

#pragma unroll
  for (int m = 0; m < 4; ++m)
#pragma unroll
    for (int n = 0; n < 4; ++n)
#pragma unroll
      for (int r = 0; r < 4; ++r) {
        const int row_g = brow + wr * 64 + m * 16 + (lane >> 4) * 4 + r;
        const int col_g = bcol + wc * 64 + n * 16 + (lane & 15);
        float vv = acc[m][n][r] + bias[col_g];
        if (EPI == 2) vv += keyp[(size_t)(row_g & (NKV_ - 1)) * DQ_ + col_g];
        C[(size_t)row_g * DQ_ + col_g] = (f16)vv;
      }
}

// ---------------------------------------------------------------------------
// Score GEMM: attn_raw = qp . km^T, pure fp16 single product.
// 256x256 tile, 512 threads (8 waves), wave-owned 128x64 tiles (2Mx4N),
// 16x16x32_f16 MFMA. K-chunk = 32 (64B LDS rows, 4 16B slots, XOR slot
// swizzle ^(row&3) -- proven-zero-conflict 16-row/4-slot read shape).
// Double-buffered 64KB static LDS; one vmcnt(0)+s_barrier per chunk.
// Per chunk/wave: 12 ds_read_b128, 32 MFMA.
// ---------------------------------------------------------------------------
__global__ __launch_bounds__(512, 2)
void score_gemm(const f16* __restrict__ qp, const f16* __restrict__ km,
                float* __restrict__ attn)
{
  __shared__ f16 ABuf[2 * 8192];   // [parity][256 rows][32]
  __shared__ f16 BBuf[2 * 8192];

  const int swz  = xcd_swz(blockIdx.x, gridDim.x);   // 512 blocks
  const int bx   = swz & 7;           // NKV block (256)
  const int by   = (swz >> 3) & 7;    // NQ block (256)
  const int b    = swz >> 6;          // batch

  const int t    = threadIdx.x;       // 0..511
  const int lane = t & 63;
  const int w    = t >> 6;            // 0..7
  const int wr   = w >> 2;            // 0..1 (M: rows wr*128..+128)
  const int wcn  = w & 3;             // 0..3 (N: cols wcn*64..+64)
  const int brow = by * 256;
  const int bcol = bx * 256;
  const int fr   = lane & 15;
  const int q    = lane >> 4;
  const int slotE = ((q ^ (fr & 3)) * 8);   // element offset within 32-elem row

  // staging: thread t -> row srow = t>>2 (0..127; +128 for issue 1),
  // phys slot t&3, logical sig = (t&3)^(srow&3).
  const int srow = t >> 2;
  const int sig  = (t & 3) ^ (srow & 3);
  const f16* aG = qp + ((size_t)b * NQ_  + brow + srow) * DQ_ + sig * 8;
  const f16* bG = km + ((size_t)b * NKV_ + bcol + srow) * DQ_ + sig * 8;

#define STAGE_A(kc) do { \
    const f16* s_ = aG + (kc) * 32; \
    f16* d_ = ABuf + ((kc) & 1) * 8192 + w * 512; \
    gload_lds16(s_, d_); \
    gload_lds16(s_ + (size_t)128 * DQ_, d_ + 4096); } while (0)
#define STAGE_B(kc) do { \
    const f16* s_ = bG + (kc) * 32; \
    f16* d_ = BBuf + ((kc) & 1) * 8192 + w * 512; \
    gload_lds16(s_, d_); \
    gload_lds16(s_ + (size_t)128 * DQ_, d_ + 4096); } while (0)

  f32x4 acc[8][4] = {};   // wave-owned 128x64: 8 m-frags x 4 n-frags

  STAGE_A(0); STAGE_B(0);
  asm volatile("s_waitcnt vmcnt(0)\n\ts_barrier" ::: "memory");

  for (int c = 0; c < 16; ++c) {
    if (c + 1 < 16) { STAGE_A(c + 1); STAGE_B(c + 1); }

    const f16* Ab = ABuf + (c & 1) * 8192;
    const f16* Bb = BBuf + (c & 1) * 8192;

    f16x8 bh[4];
#pragma unroll
    for (int ni = 0; ni < 4; ++ni)
      bh[ni] = *(const f16x8*)&Bb[(wcn * 64 + ni * 16 + fr) * 32 + slotE];

    __builtin_amdgcn_s_setprio(1);
#pragma unroll
    for (int mi = 0; mi < 8; ++mi) {
      const f16x8 ah = *(const f16x8*)&Ab[(wr * 128 + mi * 16 + fr) * 32 + slotE];
#pragma unroll
      for (int ni = 0; ni < 4; ++ni)
        acc[mi][ni] = mfma16f(ah, bh[ni], acc[mi][ni]);
    }
    __builtin_amdgcn_s_setprio(0);

    if (c + 1 < 16)
      asm volatile("s_waitcnt vmcnt(0)\n\ts_barrier" ::: "memory");
  }
#undef STAGE_A
#undef STAGE_B

  float* Cg = attn + (size_t)b * NQ_ * NKV_;
#pragma unroll
  for (int mi = 0; mi < 8; ++mi)
#pragma unroll
    for (int ni = 0; ni < 4; ++ni)
#pragma unroll
      for (int r = 0; r < 4; ++r) {
        const int row_g = brow + wr * 128 + mi * 16 + q * 4 + r;
        const int col_g = bcol + wcn * 64 + ni * 16 + fr;
        Cg[(size_t)row_g * NKV_ + col_g] = acc[mi][ni][r];
      }
}

// ---------------------------------------------------------------------------
// PV GEMM: out[b,q,n] = sum_j attnb[b,q,j] * xT[b,n,j]. fp16 operands,
// double-buffered 2-phase (proven R8 structure, 128B rows, 8 slots, 0 confl).
// ---------------------------------------------------------------------------
__global__ __launch_bounds__(256, 2)
void pv_gemm(const f16* __restrict__ attnb, const f16* __restrict__ xT,
             float* __restrict__ out)
{
  __shared__ f16 At[2][128 * 64];
  __shared__ f16 Bt[2][128 * 64];

  const int swz  = xcd_swz(blockIdx.x, gridDim.x);
  const int bx   = swz & 3;           // DIN block
  const int by   = (swz >> 2) & 15;   // NQ block
  const int b    = swz >> 6;          // batch

  const int t    = threadIdx.x;
  const int lane = t & 63;
  const int w    = t >> 6;
  const int wr   = w >> 1;
  const int wc   = w & 1;
  const int brow = by * 128;   // q rows
  const int bcol = bx * 128;   // din cols

  const int srow  = t >> 3;
  const int sslot = t & 7;
  const int sig   = sslot ^ (srow & 7);
  const f16* aG = attnb + ((size_t)b * NQ_ + brow + srow) * NKV_ + sig * 8;
  const f16* bG = xT + (size_t)b * DIN_ * NKV_ + (size_t)(bcol + srow) * NKV_ + sig * 8;

  f32x4 acc[4][4] = {};
  const int fr = lane & 15;
  const int q  = lane >> 4;

#define PV_STAGE(ks, buf) do { \
    const f16* a_ = aG + (size_t)(ks) * 64; \
    const f16* b_ = bG + (size_t)(ks) * 64; \
    f16* al_ = At[buf] + w * 512; \
    f16* bl_ = Bt[buf] + w * 512; \
    _Pragma("unroll") for (int i = 0; i < 4; ++i) { \
      gload_lds16(a_ + (size_t)i * 32 * NKV_, al_ + i * 2048); \
      gload_lds16(b_ + (size_t)i * 32 * NKV_, bl_ + i * 2048); } } while (0)

  PV_STAGE(0, 0);
  asm volatile("s_waitcnt vmcnt(0)\n\ts_barrier" ::: "memory");

  for (int ks = 0; ks < NKV_ / 64; ++ks) {
    const int cur = ks & 1;
    if (ks + 1 < NKV_ / 64) PV_STAGE(ks + 1, cur ^ 1);

    const f16* Ac = At[cur];
    const f16* Bc = Bt[cur];
#pragma unroll
    for (int kk = 0; kk < 2; ++kk) {
      f16x8 ah[4], bh[4];
#pragma unroll
      for (int m = 0; m < 4; ++m) {
        const int rt = wr * 64 + m * 16 + fr;
        ah[m] = *(const f16x8*)&Ac[rt * 64 + (((kk * 4 + q) ^ (rt & 7)) * 8)];
      }
#pragma unroll
      for (int n = 0; n < 4; ++n) {
        const int rt = wc * 64 + n * 16 + fr;
        bh[n] = *(const f16x8*)&Bc[rt * 64 + (((kk * 4 + q) ^ (rt & 7)) * 8)];
      }
#pragma unroll
      for (int m = 0; m < 4; ++m)
#pragma unroll
        for (int n = 0; n < 4; ++n)
          acc[m][n] = mfma16f(ah[m], bh[n], acc[m][n]);
    }
    asm volatile("s_waitcnt vmcnt(0)\n\ts_barrier" ::: "memory");
  }
#undef PV_STAGE

  float* Cg = out + (size_t)b * NQ_ * DIN_;
#pragma unroll
  for (int m = 0; m < 4; ++m)
#pragma unroll
    for (int n = 0; n < 4; ++n)
#pragma unroll
      for (int r = 0; r < 4; ++r) {
        const int row_g = brow + wr * 64 + m * 16 + q * 4 + r;
        const int col_g = bcol + wc * 64 + n * 16 + fr;
        Cg[(size_t)row_g * DIN_ + col_g] = acc[m][n][r];
      }
}

// ---------------------------------------------------------------------------
// x [B, NKV, DIN] fp32 -> xT [B, DIN, NKV] fp16
// ---------------------------------------------------------------------------
__global__ void transpose_x(const float* __restrict__ x, f16* __restrict__ xT)
{
  __shared__ float tile[32][33];
  const int b  = blockIdx.z;
  const int j0 = blockIdx.x * 32;   // NKV index
  const int i0 = blockIdx.y * 32;   // DIN index
  const float* xs = x  + (size_t)b * NKV_ * DIN_;
  f16*         xd = xT + (size_t)b * DIN_ * NKV_;
  const int tx = threadIdx.x, ty = threadIdx.y;  // 32 x 8
#pragma unroll
  for (int p = 0; p < 32; p += 8)
    tile[ty + p][tx] = xs[(size_t)(j0 + ty + p) * DIN_ + i0 + tx];
  __syncthreads();
#pragma unroll
  for (int p = 0; p < 32; p += 8)
    xd[(size_t)(i0 + ty + p) * NKV_ + j0 + tx] = (f16)tile[tx][ty + p];
}

// ---------------------------------------------------------------------------
// In-place row softmax over attn [rows x 2048]; also writes fp16 copy.
// ---------------------------------------------------------------------------
__global__ void softmax_rows(float* __restrict__ attn, f16* __restrict__ attnb)
{
  const int lane = threadIdx.x & 63;
  const int wv   = threadIdx.x >> 6;
  const size_t row = (size_t)blockIdx.x * 4 + wv;
  float* p  = attn  + row * NKV_;
  f16*   pb = attnb + row * NKV_;

  float4 v[8];
  float mx = -1e30f;
#pragma unroll
  for (int i = 0; i < 8; ++i) {
    v[i] = *(const float4*)&p[i * 256 + lane * 4];
    mx = fmaxf(mx, fmaxf(fmaxf(v[i].x, v[i].y), fmaxf(v[i].z, v[i].w)));
  }
#pragma unroll
  for (int off = 32; off; off >>= 1) mx = fmaxf(mx, __shfl_xor(mx, off, 64));

  float sum = 0.f;
#pragma unroll
  for (int i = 0; i < 8; ++i) {
    v[i].x = expf(v[i].x - mx);
    v[i].y = expf(v[i].y - mx);
    v[i].z = expf(v[i].z - mx);
    v[i].w = expf(v[i].w - mx);
    sum += v[i].x + v[i].y + v[i].z + v[i].w;
  }
#pragma unroll
  for (int off = 32; off; off >>= 1) sum += __shfl_xor(sum, off, 64);

  const float inv = 1.0f / sum;
#pragma unroll
  for (int i = 0; i < 8; ++i) {
    v[i].x *= inv; v[i].y *= inv; v[i].z *= inv; v[i].w *= inv;
    *(float4*)&p[i * 256 + lane * 4] = v[i];
    f16x4 hv;
    hv[0] = (f16)v[i].x; hv[1] = (f16)v[i].y;
    hv[2] = (f16)v[i].z; hv[3] = (f16)v[i].w;
    *(f16x4*)&pb[i * 256 + lane * 4] = hv;
  }
}

// ---------------------------------------------------------------------------
extern "C" void kernel_launch(void* const* d_in, const int* in_sizes, int n_in,
                              void* d_out, int out_size, void* d_ws, size_t ws_size,
                              hipStream_t stream)
{
  (void)in_sizes; (void)n_in; (void)out_size; (void)ws_size;
  const float* query  = (const float*)d_in[0];  // [8, 2048, 512]
  const float* key    = (const float*)d_in[1];  // [2048, 512]
  const float* x      = (const float*)d_in[2];  // [8, 2048, 512]
  const float* W_proj = (const float*)d_in[3];  // [512, 512]
  const float* b_proj = (const float*)d_in[4];  // [512]
  const float* W_px   = (const float*)d_in[5];  // [512, 512]
  const float* b_px   = (const float*)d_in[6];  // [512]

  float* out  = (float*)d_out;                          // [8, 2048, 512]
  float* attn = out + (size_t)B_ * NQ_ * DIN_;          // [8, 2048, 2048]

  const size_t PQE = (size_t)B_ * NQ_ * DQ_;            // 8.39M elements
  // ws layout (fp16): [xT | qp | km | ...]; after score, qp/km are dead and
  // attnb (4*PQE elems) starts at qp, extending 2*PQE past km into free ws.
  // Total ws use = 5*PQE*2B = 83.9 MB.
  f16* xT = (f16*)d_ws;           // [8, 512, 2048]
  f16* qp = xT + PQE;             // [16384, 512]
  f16* km = qp + PQE;             // [16384, 512]
  f16* attnb = qp;                // [8, 2048, 2048] fp16 (reuses qp/km + free)

  // x^T (fp16) for the PV GEMM B-operand
  transpose_x<<<dim3(NKV_ / 32, DIN_ / 32, B_), dim3(32, 8), 0, stream>>>(x, xT);

  // q_proj = query @ W_proj^T + b_proj  -> fp16
  proj_gemm<1><<<dim3(DQ_ / 128, (B_ * NQ_) / 128, 1), 256, 0, stream>>>(
      query, W_proj, qp, b_proj, nullptr);

  // k = x @ W_px^T + b_px + key        -> fp16
  proj_gemm<2><<<dim3(DQ_ / 128, (B_ * NQ_) / 128, 1), 256, 0, stream>>>(
      x, W_px, km, b_px, key);

  // raw scores into attn region of d_out (256^2 tiles, XCD-swizzled)
  score_gemm<<<(NKV_ / 256) * (NQ_ / 256) * B_, 512, 0, stream>>>(qp, km, attn);

  // softmax rows in place + fp16 copy into ws
  softmax_rows<<<(B_ * NQ_) / 4, 256, 0, stream>>>(attn, attnb);

  // out[b] = attn[b] @ x[b]  (1D grid, XCD-swizzled)
  pv_gemm<<<(DIN_ / 128) * (NQ_ / 128) * B_, 256, 0, stream>>>(attnb, xT, out);
}

// Round 16
// 221.993 us; speedup vs baseline: 1.8928x; 1.0203x over previous
//
#include <hip/hip_runtime.h>
#include <hip/hip_bf16.h>

// Problem constants
#define B_   8
#define NQ_  2048
#define NKV_ 2048
#define DQ_  512
#define DIN_ 512

using f32x4 = __attribute__((ext_vector_type(4))) float;
using f16   = _Float16;
using f16x4 = __attribute__((ext_vector_type(4))) _Float16;
using f16x8 = __attribute__((ext_vector_type(8))) _Float16;

__device__ __forceinline__ f32x4 mfma16f(f16x8 a, f16x8 b, f32x4 c) {
  return __builtin_amdgcn_mfma_f32_16x16x32_f16(a, b, c, 0, 0, 0);
}

// async global->LDS, 16B per lane. LDS dest is wave-uniform base (+lane*16 in HW).
__device__ __forceinline__ void gload_lds16(const void* g, void* l) {
  __builtin_amdgcn_global_load_lds(
      (const __attribute__((address_space(1))) void*)g,
      (__attribute__((address_space(3))) void*)l, 16, 0, 0);
}

// bijective XCD-aware remap (nwg % 8 == 0)
__device__ __forceinline__ int xcd_swz(int bid, int nwg) {
  const int c = nwg >> 3;
  return (bid & 7) * c + (bid >> 3);
}

// ---------------------------------------------------------------------------
// Fused front-end, one launch, grid (4, 128, 3):
//   z=0: qp = query @ W_proj^T + b_proj            (proj GEMM)
//   z=1: km = x @ W_px^T + b_px + key              (proj GEMM)
//   z=2: xT = transpose(x) fp16                    (dedicated blocks)
// z=1 and z=2 read x in the same window -> second read L3-served.
// GEMM path: fp32 in, fp16 out, single fp16 product, T14 reg preload.
// ---------------------------------------------------------------------------
__global__ __launch_bounds__(256, 2)
void proj_fused(const float* __restrict__ query, const float* __restrict__ W_proj,
                const float* __restrict__ b_proj, f16* __restrict__ qp,
                const float* __restrict__ x, const float* __restrict__ W_px,
                const float* __restrict__ b_px, const float* __restrict__ keyp,
                f16* __restrict__ km, f16* __restrict__ xTp)
{
  constexpr int PAD = 8;
  __shared__ f16 Ah[128][64 + PAD];
  __shared__ f16 Bh[128][64 + PAD];
  __shared__ float tt[32][33];

  const int tid = threadIdx.x;

  // ---------------- z=2: transpose blocks ----------------
  if (blockIdx.z == 2) {
    const int b  = blockIdx.y >> 4;
    const int j0 = (blockIdx.y & 15) * 128;   // NKV base
    const int d0 = blockIdx.x * 128;          // DIN base
    const float* xs = x   + (size_t)b * NKV_ * DIN_;
    f16*         xd = xTp + (size_t)b * DIN_ * NKV_;
    const int tx = tid & 31, ty = tid >> 5;   // 32 x 8
#pragma unroll
    for (int s = 0; s < 16; ++s) {
      const int jj = j0 + (s & 3) * 32;
      const int dd = d0 + (s >> 2) * 32;
      __syncthreads();
#pragma unroll
      for (int p = 0; p < 32; p += 8)
        tt[ty + p][tx] = xs[(size_t)(jj + ty + p) * DIN_ + dd + tx];
      __syncthreads();
#pragma unroll
      for (int p = 0; p < 32; p += 8)
        xd[(size_t)(dd + ty + p) * NKV_ + jj + tx] = (f16)tt[tx][ty + p];
    }
    return;
  }

  // ---------------- z=0/1: projection GEMM ----------------
  const bool second = (blockIdx.z == 1);
  const float* A    = second ? x    : query;
  const float* Bm   = second ? W_px : W_proj;
  const float* bias = second ? b_px : b_proj;
  f16*         C    = second ? km   : qp;

  const int lane = tid & 63;
  const int w    = tid >> 6;
  const int wr   = w >> 1;
  const int wc   = w & 1;
  const int brow = blockIdx.y * 128;
  const int bcol = blockIdx.x * 128;

  const float* Ag = A  + (size_t)brow * DQ_;
  const float* Bg = Bm + (size_t)bcol * DQ_;

  f32x4 acc[4][4] = {};

  const int sr = tid >> 4;
  const int sc = (tid & 15) * 4;

  float4 pa[8], pb[8];
#pragma unroll
  for (int p = 0; p < 8; ++p) {
    pa[p] = *(const float4*)(Ag + (size_t)(p * 16 + sr) * DQ_ + sc);
    pb[p] = *(const float4*)(Bg + (size_t)(p * 16 + sr) * DQ_ + sc);
  }

  for (int k0 = 0; k0 < DQ_; k0 += 64) {
    __syncthreads();
#pragma unroll
    for (int p = 0; p < 8; ++p) {
      const int r = p * 16 + sr;
      f16x4 ha, hb;
      ha[0] = (f16)pa[p].x; ha[1] = (f16)pa[p].y;
      ha[2] = (f16)pa[p].z; ha[3] = (f16)pa[p].w;
      hb[0] = (f16)pb[p].x; hb[1] = (f16)pb[p].y;
      hb[2] = (f16)pb[p].z; hb[3] = (f16)pb[p].w;
      *(f16x4*)&Ah[r][sc] = ha;
      *(f16x4*)&Bh[r][sc] = hb;
    }
    if (k0 + 64 < DQ_) {
#pragma unroll
      for (int p = 0; p < 8; ++p) {
        pa[p] = *(const float4*)(Ag + (size_t)(p * 16 + sr) * DQ_ + k0 + 64 + sc);
        pb[p] = *(const float4*)(Bg + (size_t)(p * 16 + sr) * DQ_ + k0 + 64 + sc);
      }
    }
    __syncthreads();
#pragma unroll
    for (int kk = 0; kk < 2; ++kk) {
      const int fr = lane & 15;
      const int fc = kk * 32 + (lane >> 4) * 8;
      f16x8 ah[4], bh[4];
#pragma unroll
      for (int m = 0; m < 4; ++m)
        ah[m] = *(const f16x8*)&Ah[wr * 64 + m * 16 + fr][fc];
#pragma unroll
      for (int n = 0; n < 4; ++n)
        bh[n] = *(const f16x8*)&Bh[wc * 64 + n * 16 + fr][fc];
#pragma unroll
      for (int m = 0; m < 4; ++m)
#pragma unroll
        for (int n = 0; n < 4; ++n)
          acc[m][n] = mfma16f(ah[m], bh[n], acc[m][n]);
    }
  }

#pragma unroll
  for (int m = 0; m < 4; ++m)
#pragma unroll
    for (int n = 0; n < 4; ++n)
#pragma unroll
      for (int r = 0; r < 4; ++r) {
        const int row_g = brow + wr * 64 + m * 16 + (lane >> 4) * 4 + r;
        const int col_g = bcol + wc * 64 + n * 16 + (lane & 15);
        float vv = acc[m][n][r] + bias[col_g];
        if (second) vv += keyp[(size_t)(row_g & (NKV_ - 1)) * DQ_ + col_g];
        C[(size_t)row_g * DQ_ + col_g] = (f16)vv;
      }
}

// ---------------------------------------------------------------------------
// Score GEMM: attn_raw = qp . km^T, pure fp16 single product.
// 256x256 tile, 512 threads (8 waves), wave-owned 128x64 tiles (2Mx4N),
// 16x16x32_f16 MFMA. K-chunk = 32 (64B LDS rows, 4 16B slots, XOR slot
// swizzle ^(row&3) -- proven-zero-conflict 16-row/4-slot read shape).
// Double-buffered 64KB static LDS; one vmcnt(0)+s_barrier per chunk.
// ---------------------------------------------------------------------------
__global__ __launch_bounds__(512, 2)
void score_gemm(const f16* __restrict__ qp, const f16* __restrict__ km,
                float* __restrict__ attn)
{
  __shared__ f16 ABuf[2 * 8192];   // [parity][256 rows][32]
  __shared__ f16 BBuf[2 * 8192];

  const int swz  = xcd_swz(blockIdx.x, gridDim.x);   // 512 blocks
  const int bx   = swz & 7;           // NKV block (256)
  const int by   = (swz >> 3) & 7;    // NQ block (256)
  const int b    = swz >> 6;          // batch

  const int t    = threadIdx.x;       // 0..511
  const int lane = t & 63;
  const int w    = t >> 6;            // 0..7
  const int wr   = w >> 2;            // 0..1 (M: rows wr*128..+128)
  const int wcn  = w & 3;             // 0..3 (N: cols wcn*64..+64)
  const int brow = by * 256;
  const int bcol = bx * 256;
  const int fr   = lane & 15;
  const int q    = lane >> 4;
  const int slotE = ((q ^ (fr & 3)) * 8);   // element offset within 32-elem row

  const int srow = t >> 2;
  const int sig  = (t & 3) ^ (srow & 3);
  const f16* aG = qp + ((size_t)b * NQ_  + brow + srow) * DQ_ + sig * 8;
  const f16* bG = km + ((size_t)b * NKV_ + bcol + srow) * DQ_ + sig * 8;

#define STAGE_A(kc) do { \
    const f16* s_ = aG + (kc) * 32; \
    f16* d_ = ABuf + ((kc) & 1) * 8192 + w * 512; \
    gload_lds16(s_, d_); \
    gload_lds16(s_ + (size_t)128 * DQ_, d_ + 4096); } while (0)
#define STAGE_B(kc) do { \
    const f16* s_ = bG + (kc) * 32; \
    f16* d_ = BBuf + ((kc) & 1) * 8192 + w * 512; \
    gload_lds16(s_, d_); \
    gload_lds16(s_ + (size_t)128 * DQ_, d_ + 4096); } while (0)

  f32x4 acc[8][4] = {};   // wave-owned 128x64: 8 m-frags x 4 n-frags

  STAGE_A(0); STAGE_B(0);
  asm volatile("s_waitcnt vmcnt(0)\n\ts_barrier" ::: "memory");

  for (int c = 0; c < 16; ++c) {
    if (c + 1 < 16) { STAGE_A(c + 1); STAGE_B(c + 1); }

    const f16* Ab = ABuf + (c & 1) * 8192;
    const f16* Bb = BBuf + (c & 1) * 8192;

    f16x8 bh[4];
#pragma unroll
    for (int ni = 0; ni < 4; ++ni)
      bh[ni] = *(const f16x8*)&Bb[(wcn * 64 + ni * 16 + fr) * 32 + slotE];

    __builtin_amdgcn_s_setprio(1);
#pragma unroll
    for (int mi = 0; mi < 8; ++mi) {
      const f16x8 ah = *(const f16x8*)&Ab[(wr * 128 + mi * 16 + fr) * 32 + slotE];
#pragma unroll
      for (int ni = 0; ni < 4; ++ni)
        acc[mi][ni] = mfma16f(ah, bh[ni], acc[mi][ni]);
    }
    __builtin_amdgcn_s_setprio(0);

    if (c + 1 < 16)
      asm volatile("s_waitcnt vmcnt(0)\n\ts_barrier" ::: "memory");
  }
#undef STAGE_A
#undef STAGE_B

  float* Cg = attn + (size_t)b * NQ_ * NKV_;
#pragma unroll
  for (int mi = 0; mi < 8; ++mi)
#pragma unroll
    for (int ni = 0; ni < 4; ++ni)
#pragma unroll
      for (int r = 0; r < 4; ++r) {
        const int row_g = brow + wr * 128 + mi * 16 + q * 4 + r;
        const int col_g = bcol + wcn * 64 + ni * 16 + fr;
        Cg[(size_t)row_g * NKV_ + col_g] = acc[mi][ni][r];
      }
}

// ---------------------------------------------------------------------------
// PV GEMM: out[b,q,n] = sum_j attnb[b,q,j] * xT[b,n,j]. fp16 operands,
// double-buffered 2-phase (proven R8 structure, 128B rows, 8 slots, 0 confl).
// ---------------------------------------------------------------------------
__global__ __launch_bounds__(256, 2)
void pv_gemm(const f16* __restrict__ attnb, const f16* __restrict__ xT,
             float* __restrict__ out)
{
  __shared__ f16 At[2][128 * 64];
  __shared__ f16 Bt[2][128 * 64];

  const int swz  = xcd_swz(blockIdx.x, gridDim.x);
  const int bx   = swz & 3;           // DIN block
  const int by   = (swz >> 2) & 15;   // NQ block
  const int b    = swz >> 6;          // batch

  const int t    = threadIdx.x;
  const int lane = t & 63;
  const int w    = t >> 6;
  const int wr   = w >> 1;
  const int wc   = w & 1;
  const int brow = by * 128;   // q rows
  const int bcol = bx * 128;   // din cols

  const int srow  = t >> 3;
  const int sslot = t & 7;
  const int sig   = sslot ^ (srow & 7);
  const f16* aG = attnb + ((size_t)b * NQ_ + brow + srow) * NKV_ + sig * 8;
  const f16* bG = xT + (size_t)b * DIN_ * NKV_ + (size_t)(bcol + srow) * NKV_ + sig * 8;

  f32x4 acc[4][4] = {};
  const int fr = lane & 15;
  const int q  = lane >> 4;

#define PV_STAGE(ks, buf) do { \
    const f16* a_ = aG + (size_t)(ks) * 64; \
    const f16* b_ = bG + (size_t)(ks) * 64; \
    f16* al_ = At[buf] + w * 512; \
    f16* bl_ = Bt[buf] + w * 512; \
    _Pragma("unroll") for (int i = 0; i < 4; ++i) { \
      gload_lds16(a_ + (size_t)i * 32 * NKV_, al_ + i * 2048); \
      gload_lds16(b_ + (size_t)i * 32 * NKV_, bl_ + i * 2048); } } while (0)

  PV_STAGE(0, 0);
  asm volatile("s_waitcnt vmcnt(0)\n\ts_barrier" ::: "memory");

  for (int ks = 0; ks < NKV_ / 64; ++ks) {
    const int cur = ks & 1;
    if (ks + 1 < NKV_ / 64) PV_STAGE(ks + 1, cur ^ 1);

    const f16* Ac = At[cur];
    const f16* Bc = Bt[cur];
#pragma unroll
    for (int kk = 0; kk < 2; ++kk) {
      f16x8 ah[4], bh[4];
#pragma unroll
      for (int m = 0; m < 4; ++m) {
        const int rt = wr * 64 + m * 16 + fr;
        ah[m] = *(const f16x8*)&Ac[rt * 64 + (((kk * 4 + q) ^ (rt & 7)) * 8)];
      }
#pragma unroll
      for (int n = 0; n < 4; ++n) {
        const int rt = wc * 64 + n * 16 + fr;
        bh[n] = *(const f16x8*)&Bc[rt * 64 + (((kk * 4 + q) ^ (rt & 7)) * 8)];
      }
#pragma unroll
      for (int m = 0; m < 4; ++m)
#pragma unroll
        for (int n = 0; n < 4; ++n)
          acc[m][n] = mfma16f(ah[m], bh[n], acc[m][n]);
    }
    asm volatile("s_waitcnt vmcnt(0)\n\ts_barrier" ::: "memory");
  }
#undef PV_STAGE

  float* Cg = out + (size_t)b * NQ_ * DIN_;
#pragma unroll
  for (int m = 0; m < 4; ++m)
#pragma unroll
    for (int n = 0; n < 4; ++n)
#pragma unroll
      for (int r = 0; r < 4; ++r) {
        const int row_g = brow + wr * 64 + m * 16 + q * 4 + r;
        const int col_g = bcol + wc * 64 + n * 16 + fr;
        Cg[(size_t)row_g * DIN_ + col_g] = acc[m][n][r];
      }
}

// ---------------------------------------------------------------------------
// In-place row softmax over attn [rows x 2048]; also writes fp16 copy.
// ---------------------------------------------------------------------------
__global__ void softmax_rows(float* __restrict__ attn, f16* __restrict__ attnb)
{
  const int lane = threadIdx.x & 63;
  const int wv   = threadIdx.x >> 6;
  const size_t row = (size_t)blockIdx.x * 4 + wv;
  float* p  = attn  + row * NKV_;
  f16*   pb = attnb + row * NKV_;

  float4 v[8];
  float mx = -1e30f;
#pragma unroll
  for (int i = 0; i < 8; ++i) {
    v[i] = *(const float4*)&p[i * 256 + lane * 4];
    mx = fmaxf(mx, fmaxf(fmaxf(v[i].x, v[i].y), fmaxf(v[i].z, v[i].w)));
  }
#pragma unroll
  for (int off = 32; off; off >>= 1) mx = fmaxf(mx, __shfl_xor(mx, off, 64));

  float sum = 0.f;
#pragma unroll
  for (int i = 0; i < 8; ++i) {
    v[i].x = expf(v[i].x - mx);
    v[i].y = expf(v[i].y - mx);
    v[i].z = expf(v[i].z - mx);
    v[i].w = expf(v[i].w - mx);
    sum += v[i].x + v[i].y + v[i].z + v[i].w;
  }
#pragma unroll
  for (int off = 32; off; off >>= 1) sum += __shfl_xor(sum, off, 64);

  const float inv = 1.0f / sum;
#pragma unroll
  for (int i = 0; i < 8; ++i) {
    v[i].x *= inv; v[i].y *= inv; v[i].z *= inv; v[i].w *= inv;
    *(float4*)&p[i * 256 + lane * 4] = v[i];
    f16x4 hv;
    hv[0] = (f16)v[i].x; hv[1] = (f16)v[i].y;
    hv[2] = (f16)v[i].z; hv[3] = (f16)v[i].w;
    *(f16x4*)&pb[i * 256 + lane * 4] = hv;
  }
}

// ---------------------------------------------------------------------------
extern "C" void kernel_launch(void* const* d_in, const int* in_sizes, int n_in,
                              void* d_out, int out_size, void* d_ws, size_t ws_size,
                              hipStream_t stream)
{
  (void)in_sizes; (void)n_in; (void)out_size; (void)ws_size;
  const float* query  = (const float*)d_in[0];  // [8, 2048, 512]
  const float* key    = (const float*)d_in[1];  // [2048, 512]
  const float* x      = (const float*)d_in[2];  // [8, 2048, 512]
  const float* W_proj = (const float*)d_in[3];  // [512, 512]
  const float* b_proj = (const float*)d_in[4];  // [512]
  const float* W_px   = (const float*)d_in[5];  // [512, 512]
  const float* b_px   = (const float*)d_in[6];  // [512]

  float* out  = (float*)d_out;                          // [8, 2048, 512]
  float* attn = out + (size_t)B_ * NQ_ * DIN_;          // [8, 2048, 2048]

  const size_t PQE = (size_t)B_ * NQ_ * DQ_;            // 8.39M elements
  // ws layout (fp16): [xT | qp | km | ...]; after score, qp/km are dead and
  // attnb (4*PQE elems) starts at qp, extending 2*PQE past km into free ws.
  // Total ws use = 5*PQE*2B = 83.9 MB.
  f16* xT = (f16*)d_ws;           // [8, 512, 2048]
  f16* qp = xT + PQE;             // [16384, 512]
  f16* km = qp + PQE;             // [16384, 512]
  f16* attnb = qp;                // [8, 2048, 2048] fp16 (reuses qp/km + free)

  // fused front-end: z=0 qp-proj, z=1 km-proj, z=2 xT transpose
  proj_fused<<<dim3(DQ_ / 128, (B_ * NQ_) / 128, 3), 256, 0, stream>>>(
      query, W_proj, b_proj, qp, x, W_px, b_px, key, km, xT);

  // raw scores into attn region of d_out (256^2 tiles, XCD-swizzled)
  score_gemm<<<(NKV_ / 256) * (NQ_ / 256) * B_, 512, 0, stream>>>(qp, km, attn);

  // softmax rows in place + fp16 copy into ws
  softmax_rows<<<(B_ * NQ_) / 4, 256, 0, stream>>>(attn, attnb);

  // out[b] = attn[b] @ x[b]  (1D grid, XCD-swizzled)
  pv_gemm<<<(DIN_ / 128) * (NQ_ / 128) * B_, 256, 0, stream>>>(attnb, xT, out);
}